// Round 4
// baseline (88.435 us; speedup 1.0000x reference)
//
#include <hip/hip_runtime.h>
#include <hip/hip_bf16.h>
#include <stdint.h>

#define N_VOX 65536
#define NK 27
#define BR 64          // rows per block

typedef float f32x4 __attribute__((ext_vector_type(4)));
typedef __bf16 bf16x8 __attribute__((ext_vector_type(8)));

#define WAITVM(n) asm volatile("s_waitcnt vmcnt(" #n ")" ::: "memory")

__device__ __forceinline__ void barrier_fence() {
    asm volatile("" ::: "memory");
    __builtin_amdgcn_s_barrier();
    asm volatile("" ::: "memory");
}

// async global->LDS, 16B per lane; LDS dest = M0 + lane*16 (wave-uniform M0)
__device__ __forceinline__ void gll16(const void* src, uint32_t lds_addr) {
    asm volatile("s_mov_b32 m0, %0\n\t"
                 "global_load_lds_dwordx4 %1, off"
                 :: "s"(lds_addr), "v"(src)
                 : "memory");
}

// direct global->VGPR 16B load (A fragment), per-lane address
__device__ __forceinline__ f32x4 gload16(const void* src) {
    f32x4 r;
    uint64_t ad = (uint64_t)(uintptr_t)src;
    asm volatile("global_load_dwordx4 %0, %1, off"
                 : "=v"(r) : "v"(ad) : "memory");
    return r;
}

// W[k][c][d] f32 -> Wt pre-swizzled bf16 so a LINEAR 1KB-per-wave global_load_lds
// produces the XOR-swizzled LDS image directly (inverse-swz source + swz read).
__device__ __forceinline__ void wconv_elem(const float* __restrict__ W,
                                           __bf16* __restrict__ Wt, int Dc, int i) {
    int d = i % Dc;                 // output channel = B row
    int c = (i / Dc) % 64;          // input channel  = B col (K)
    int k = i / (Dc * 64);
    int off = ((d * 128 + ((c >> 3) << 4)) ^ ((d & 7) << 4)) + (c & 7) * 2;
    *(__bf16*)((char*)Wt + (size_t)k * Dc * 128 + off) = (__bf16)W[i];
}

// Fused prep: x f32->bf16 (2048 blocks) | W1 (432) | W2 (432) | W3 (108) | zero page (1)
#define PREP_CVT   2048
#define PREP_W1    432
#define PREP_W2    432
#define PREP_W3    108
#define PREP_GRID  (PREP_CVT + PREP_W1 + PREP_W2 + PREP_W3 + 1)
__global__ __launch_bounds__(256) void prep_kernel(
    const float* __restrict__ x,
    const float* __restrict__ W1, const float* __restrict__ W2, const float* __restrict__ W3,
    __bf16* __restrict__ xb, __bf16* __restrict__ Wt1, __bf16* __restrict__ Wt2,
    __bf16* __restrict__ Wt3, float* __restrict__ zp)
{
    const int b = blockIdx.x, tid = threadIdx.x;
    if (b < PREP_CVT) {
        int i = b * 256 + tid;                      // 8 elems/thread, exactly covers N*64
        const f32x4* xp = (const f32x4*)x;
        f32x4 f0 = xp[i * 2], f1 = xp[i * 2 + 1];
        bf16x8 v;
#pragma unroll
        for (int j = 0; j < 4; ++j) { v[j] = (__bf16)f0[j]; v[4 + j] = (__bf16)f1[j]; }
        ((bf16x8*)xb)[i] = v;
    } else if (b < PREP_CVT + PREP_W1) {
        wconv_elem(W1, Wt1, 64, (b - PREP_CVT) * 256 + tid);
    } else if (b < PREP_CVT + PREP_W1 + PREP_W2) {
        wconv_elem(W2, Wt2, 64, (b - PREP_CVT - PREP_W1) * 256 + tid);
    } else if (b < PREP_CVT + PREP_W1 + PREP_W2 + PREP_W3) {
        wconv_elem(W3, Wt3, 16, (b - PREP_CVT - PREP_W1 - PREP_W2) * 256 + tid);
    } else {
        if (tid < 16) ((f32x4*)zp)[tid] = (f32x4){0.f, 0.f, 0.f, 0.f};  // 256B zero page
    }
}

// One layer: out[n,:] = bias + sum_k feat[nbr(n,k)] @ W[k]   (invalid nbr -> 0)
// 4 waves in WR x WC grid over (rows, cols). A fragments loaded DIRECTLY from
// global into VGPRs (per-lane gather addresses, depth-2 register pipeline).
// Only B (weights) goes through LDS (double-buffered gll16, counted vmcnt).
// One barrier per k.
template <int NCOLS, bool RELU, bool OUT_F32>
__global__ __launch_bounds__(256, 4) void conv_layer(
    const __bf16* __restrict__ feat,      // [N,64] bf16
    const int* __restrict__ nidx,         // [N,27]
    const __bf16* __restrict__ Wt,        // [27][NCOLS*64] pre-swizzled bf16
    const float* __restrict__ bias,       // [NCOLS]
    void* __restrict__ dst,               // [N,NCOLS]
    const __bf16* __restrict__ zp)        // 256B zero page
{
    constexpr int WC = (NCOLS == 64) ? 2 : 1;  // col-split waves
    constexpr int WR = 4 / WC;                 // row-split waves
    constexpr int MI = BR / (WR * 16);         // 2 (CH) or 1 (COUT)
    constexpr int NI = NCOLS / (WC * 16);      // 2 (CH) or 1 (COUT)
    constexpr int BSZ = NCOLS * 128;           // B tile bytes (8K or 2K)
    constexpr int SNOFF = 2 * BSZ;
    __shared__ __align__(16) char lds[SNOFF + BR * NK * 4];

    const int tid = threadIdx.x;
    const int lane = tid & 63;
    const int wid = tid >> 6;
    const int wr = wid / WC;
    const int wc = wid % WC;
    const int col = lane & 15;
    const int kgrp = lane >> 4;
    const int row0 = blockIdx.x * BR;

    // ---- preload nidx slab (transposed: snid[k*BR + r]) ----
    int* snid = (int*)(lds + SNOFF);
    const int* gnid = nidx + (size_t)row0 * NK;
    for (int i = tid; i < BR * NK; i += 256) {
        int r = i / NK;
        int kk = i - r * NK;
        snid[kk * BR + r] = gnid[i];
    }
    __syncthreads();

    const uint32_t ldsbase = (uint32_t)(uintptr_t)(&lds[0]);
    const int uw = __builtin_amdgcn_readfirstlane(wid);
    const char* featB = (const char*)feat;
    const char* zpB = (const char*)zp;
    const int chunk = kgrp * 16;               // per-lane byte offset within row

    // issue B(k) gll16 into LDS buf p   (queue: B issued BEFORE A each iter)
    auto issueB = [&](int k, int p) {
        if constexpr (NCOLS == 64) {
#pragma unroll
            for (int j = 0; j < 2; ++j) {
                int jb = wid * 2 + j;
                const __bf16* src = Wt + (size_t)k * (NCOLS * 64) + jb * 512 + lane * 8;
                gll16(src, (uint32_t)__builtin_amdgcn_readfirstlane(
                                (int)(ldsbase + p * BSZ + jb * 1024)));
            }
        } else {
            if (uw < 2) {
                const __bf16* src = Wt + (size_t)k * (NCOLS * 64) + wid * 512 + lane * 8;
                gll16(src, (uint32_t)__builtin_amdgcn_readfirstlane(
                                (int)(ldsbase + p * BSZ + wid * 1024)));
            }
        }
    };

    // issue A(k) gather fragments directly into VGPR bank a[MI][2]
    auto issueA = [&](int k, f32x4 (&a)[MI][2]) {
#pragma unroll
        for (int mi = 0; mi < MI; ++mi) {
            int r = wr * (MI * 16) + mi * 16 + col;
            int m = snid[k * BR + r];
            const char* base = (m >= 0) ? (featB + (size_t)m * 128) : zpB;
#pragma unroll
            for (int kk = 0; kk < 2; ++kk)
                a[mi][kk] = gload16(base + kk * 64 + chunk);
        }
    };

    f32x4 acc[MI][NI];
#pragma unroll
    for (int mi = 0; mi < MI; ++mi)
#pragma unroll
        for (int ni = 0; ni < NI; ++ni)
#pragma unroll
            for (int j = 0; j < 4; ++j) acc[mi][ni][j] = 0.f;

    auto compute = [&](int k, f32x4 (&a)[MI][2]) {
        const char* Bc = lds + (k & 1) * BSZ;
        bf16x8 b[NI][2];
#pragma unroll
        for (int ni = 0; ni < NI; ++ni) {
            int br = wc * (NI * 16) + ni * 16 + col;
#pragma unroll
            for (int kk = 0; kk < 2; ++kk)
                b[ni][kk] = *(const bf16x8*)(Bc + ((br * 128 + kk * 64 + kgrp * 16)
                                                   ^ ((br & 7) << 4)));
        }
#pragma unroll
        for (int kk = 0; kk < 2; ++kk)
#pragma unroll
            for (int mi = 0; mi < MI; ++mi)
#pragma unroll
                for (int ni = 0; ni < NI; ++ni)
                    acc[mi][ni] = __builtin_amdgcn_mfma_f32_16x16x32_bf16(
                        __builtin_bit_cast(bf16x8, a[mi][kk]), b[ni][kk],
                        acc[mi][ni], 0, 0, 0);
    };

    // waits: TOP retires own B(k) (leaves A(k) in flight); MID retires A(k)
    // (leaves B(k+1)+A(k+1) in flight). Queue order per iter: B first, then A.
#define WAIT_TOP() do { if constexpr (NCOLS == 64) { WAITVM(4); } else { WAITVM(2); } } while (0)
#define WAIT_MID() do { if constexpr (NCOLS == 64) { WAITVM(6); } \
                        else { if (uw < 2) { WAITVM(3); } else { WAITVM(2); } } } while (0)

    f32x4 aA[MI][2], aB[MI][2];
    issueB(0, 0);
    issueA(0, aA);

    for (int k2 = 0; k2 < 13; ++k2) {
        const int k = 2 * k2;
        // ---- iter k (even): compute aA, prefetch k+1 into aB ----
        WAIT_TOP();                   // B(k) landed
        barrier_fence();              // all waves: B(k) visible, B(k-1) reads done
        issueB(k + 1, (k + 1) & 1);
        issueA(k + 1, aB);
        WAIT_MID();                   // A(k) landed, k+1 stays in flight
        __builtin_amdgcn_sched_barrier(0);
        compute(k, aA);
        // ---- iter k+1 (odd): compute aB, prefetch k+2 into aA ----
        WAIT_TOP();
        barrier_fence();
        issueB(k + 2, (k + 2) & 1);   // k+2 <= 26
        issueA(k + 2, aA);
        WAIT_MID();
        __builtin_amdgcn_sched_barrier(0);
        compute(k + 1, aB);
    }
    // ---- k = 26 (even parity -> aA) ----
    WAIT_TOP();
    barrier_fence();
    WAITVM(0);
    __builtin_amdgcn_sched_barrier(0);
    compute(26, aA);

#undef WAIT_TOP
#undef WAIT_MID

    // ---- epilogue: C/D layout col=lane&15, row=(lane>>4)*4+reg ----
#pragma unroll
    for (int ni = 0; ni < NI; ++ni) {
        float bv = bias[wc * (NI * 16) + ni * 16 + col];
#pragma unroll
        for (int mi = 0; mi < MI; ++mi) {
#pragma unroll
            for (int reg = 0; reg < 4; ++reg) {
                int r = row0 + wr * (MI * 16) + mi * 16 + kgrp * 4 + reg;
                int c = wc * (NI * 16) + ni * 16 + col;
                float v = acc[mi][ni][reg] + bv;
                if (RELU) v = fmaxf(v, 0.f);
                if (OUT_F32) ((float*)dst)[(size_t)r * NCOLS + c] = v;
                else ((__bf16*)dst)[(size_t)r * NCOLS + c] = (__bf16)v;
            }
        }
    }
}

extern "C" void kernel_launch(void* const* d_in, const int* in_sizes, int n_in,
                              void* d_out, int out_size, void* d_ws, size_t ws_size,
                              hipStream_t stream) {
    const float* x  = (const float*)d_in[0];
    const int* nidx = (const int*)d_in[1];
    const float* W1 = (const float*)d_in[2];
    const float* b1 = (const float*)d_in[3];
    const float* W2 = (const float*)d_in[4];
    const float* b2 = (const float*)d_in[5];
    const float* W3 = (const float*)d_in[6];
    const float* b3 = (const float*)d_in[7];

    // ws: buf0(8MB: xb, later h2) | buf1(8MB: h1) | Wt1 | Wt2 | Wt3 | zeropage
    char* ws = (char*)d_ws;
    __bf16* buf0 = (__bf16*)ws;
    __bf16* buf1 = (__bf16*)(ws + 8388608);
    __bf16* Wt1  = (__bf16*)(ws + 16777216);
    __bf16* Wt2  = Wt1 + 27 * 64 * 64;
    __bf16* Wt3  = Wt2 + 27 * 64 * 64;
    __bf16* zp   = Wt3 + 27 * 16 * 64;   // 256B-aligned

    prep_kernel<<<PREP_GRID, 256, 0, stream>>>(x, W1, W2, W3, buf0, Wt1, Wt2, Wt3, (float*)zp);

    dim3 grid(N_VOX / BR);
    conv_layer<64, true,  false><<<grid, 256, 0, stream>>>(buf0, nidx, Wt1, b1, buf1, zp);
    conv_layer<64, true,  false><<<grid, 256, 0, stream>>>(buf1, nidx, Wt2, b2, buf0, zp);
    conv_layer<16, false, true ><<<grid, 256, 0, stream>>>(buf0, nidx, Wt3, b3, d_out, zp);
}

// Round 5
// 75.590 us; speedup vs baseline: 1.1699x; 1.1699x over previous
//
#include <hip/hip_runtime.h>
#include <hip/hip_bf16.h>
#include <stdint.h>

#define N_VOX 65536
#define NK 27
#define BR 128         // rows per block

typedef float f32x4 __attribute__((ext_vector_type(4)));
typedef __bf16 bf16x8 __attribute__((ext_vector_type(8)));

#define WAITVM(n) asm volatile("s_waitcnt vmcnt(" #n ")" ::: "memory")

__device__ __forceinline__ void barrier_fence() {
    asm volatile("" ::: "memory");
    __builtin_amdgcn_s_barrier();
    asm volatile("" ::: "memory");
}

// async global->LDS, 16B per lane; LDS dest = M0 + lane*16 (wave-uniform M0)
__device__ __forceinline__ void gll16(const void* src, uint32_t lds_addr) {
    asm volatile("s_mov_b32 m0, %0\n\t"
                 "global_load_lds_dwordx4 %1, off"
                 :: "s"(lds_addr), "v"(src)
                 : "memory");
}

// W[k][c][d] f32 -> Wt pre-swizzled bf16 so a LINEAR 1KB-per-wave global_load_lds
// produces the XOR-swizzled LDS image directly (inverse-swz source + swz read).
__device__ __forceinline__ void wconv_elem(const float* __restrict__ W,
                                           __bf16* __restrict__ Wt, int Dc, int i) {
    int d = i % Dc;                 // output channel = B row
    int c = (i / Dc) % 64;          // input channel  = B col (K)
    int k = i / (Dc * 64);
    int off = ((d * 128 + ((c >> 3) << 4)) ^ ((d & 7) << 4)) + (c & 7) * 2;
    *(__bf16*)((char*)Wt + (size_t)k * Dc * 128 + off) = (__bf16)W[i];
}

// Fused prep: x f32->bf16 (2048 blocks) | W1 (432) | W2 (432) | W3 (108) | zero page (1)
#define PREP_CVT   2048
#define PREP_W1    432
#define PREP_W2    432
#define PREP_W3    108
#define PREP_GRID  (PREP_CVT + PREP_W1 + PREP_W2 + PREP_W3 + 1)
__global__ __launch_bounds__(256) void prep_kernel(
    const float* __restrict__ x,
    const float* __restrict__ W1, const float* __restrict__ W2, const float* __restrict__ W3,
    __bf16* __restrict__ xb, __bf16* __restrict__ Wt1, __bf16* __restrict__ Wt2,
    __bf16* __restrict__ Wt3, float* __restrict__ zp)
{
    const int b = blockIdx.x, tid = threadIdx.x;
    if (b < PREP_CVT) {
        int i = b * 256 + tid;                      // 8 elems/thread, exactly covers N*64
        const f32x4* xp = (const f32x4*)x;
        f32x4 f0 = xp[i * 2], f1 = xp[i * 2 + 1];
        bf16x8 v;
#pragma unroll
        for (int j = 0; j < 4; ++j) { v[j] = (__bf16)f0[j]; v[4 + j] = (__bf16)f1[j]; }
        ((bf16x8*)xb)[i] = v;
    } else if (b < PREP_CVT + PREP_W1) {
        wconv_elem(W1, Wt1, 64, (b - PREP_CVT) * 256 + tid);
    } else if (b < PREP_CVT + PREP_W1 + PREP_W2) {
        wconv_elem(W2, Wt2, 64, (b - PREP_CVT - PREP_W1) * 256 + tid);
    } else if (b < PREP_CVT + PREP_W1 + PREP_W2 + PREP_W3) {
        wconv_elem(W3, Wt3, 16, (b - PREP_CVT - PREP_W1 - PREP_W2) * 256 + tid);
    } else {
        if (tid < 16) ((f32x4*)zp)[tid] = (f32x4){0.f, 0.f, 0.f, 0.f};  // 256B zero page
    }
}

// One layer: out[n,:] = bias + sum_k feat[nbr(n,k)] @ W[k]   (invalid nbr -> 0)
// 4 row-split waves, each 32 rows (MI=2) x NCOLS (NI). BR=128 rows/block.
// Double-buffered LDS via global_load_lds, counted-vmcnt pipeline (R3-proven).
template <int NCOLS, bool RELU, bool OUT_F32>
__global__ __launch_bounds__(256, 2) void conv_layer(
    const __bf16* __restrict__ feat,      // [N,64] bf16
    const int* __restrict__ nidx,         // [N,27]
    const __bf16* __restrict__ Wt,        // [27][NCOLS*64] pre-swizzled bf16
    const float* __restrict__ bias,       // [NCOLS]
    void* __restrict__ dst,               // [N,NCOLS]
    const __bf16* __restrict__ zp)        // 256B zero page
{
    constexpr int MI = 2;                      // 32 rows per wave
    constexpr int NI = NCOLS / 16;             // 4 (CH) or 1 (COUT)
    constexpr int ABSZ = BR * 128;             // 16K A tile
    constexpr int BSZ = NCOLS * 128;           // 8K or 2K B tile
    constexpr int BOFF = 2 * ABSZ;             // A double buffer
    constexpr int SNOFF = BOFF + 2 * BSZ;
    __shared__ __align__(16) char lds[SNOFF + BR * NK * 4];

    const int tid = threadIdx.x;
    const int lane = tid & 63;
    const int wid = tid >> 6;
    const int col = lane & 15;
    const int kgrp = lane >> 4;
    const int row0 = blockIdx.x * BR;

    // ---- preload nidx slab (transposed: snid[k*BR + r]) ----
    int* snid = (int*)(lds + SNOFF);
    const int* gnid = nidx + (size_t)row0 * NK;
    for (int i = tid; i < BR * NK; i += 256) {
        int r = i / NK;
        int kk = i - r * NK;
        snid[kk * BR + r] = gnid[i];
    }
    __syncthreads();

    const uint32_t ldsbase = (uint32_t)(uintptr_t)(&lds[0]);
    const int uw = __builtin_amdgcn_readfirstlane(wid);

    // per-lane A gather geometry: thread covers 4 chunks of the 16KB A tile
    int rA[4], qA[4];
#pragma unroll
    for (int j = 0; j < 4; ++j) {
        int o = (wid * 4 + j) * 1024 + lane * 16;
        rA[j] = o >> 7;                       // row in tile 0..127
        qA[j] = ((o >> 4) & 7) ^ (rA[j] & 7); // inverse-swizzled source chunk
    }

    auto issue = [&](int k, int buf) {
        // B first (retired first at the wait)
        if constexpr (NCOLS == 64) {
#pragma unroll
            for (int j = 0; j < 2; ++j) {
                int jb = wid * 2 + j;
                const __bf16* src = Wt + (size_t)k * (NCOLS * 64) + jb * 512 + lane * 8;
                gll16(src, (uint32_t)__builtin_amdgcn_readfirstlane(
                                (int)(ldsbase + BOFF + buf * BSZ + jb * 1024)));
            }
        } else {
            if (uw < 2) {
                const __bf16* src = Wt + (size_t)k * (NCOLS * 64) + wid * 512 + lane * 8;
                gll16(src, (uint32_t)__builtin_amdgcn_readfirstlane(
                                (int)(ldsbase + BOFF + buf * BSZ + wid * 1024)));
            }
        }
        // A: 4 x 1KB per wave-chunk
#pragma unroll
        for (int j = 0; j < 4; ++j) {
            int m = snid[k * BR + rA[j]];
            const __bf16* src = (m >= 0) ? (feat + (size_t)m * 64 + qA[j] * 8) : zp;
            gll16(src, (uint32_t)__builtin_amdgcn_readfirstlane(
                            (int)(ldsbase + buf * ABSZ + (wid * 4 + j) * 1024)));
        }
    };

    f32x4 acc[MI][NI];
#pragma unroll
    for (int mi = 0; mi < MI; ++mi)
#pragma unroll
        for (int ni = 0; ni < NI; ++ni)
#pragma unroll
            for (int j = 0; j < 4; ++j) acc[mi][ni][j] = 0.f;

    issue(0, 0);

    for (int k = 0; k < NK; ++k) {
        const int cur = k & 1;
        barrier_fence();                    // readers of buf cur^1 are done
        if (k + 1 < NK) {
            issue(k + 1, cur ^ 1);
            // retire own k-loads; k+1's (just issued) stay in flight
            if constexpr (NCOLS == 64) { WAITVM(6); }
            else { if (uw < 2) { WAITVM(5); } else { WAITVM(4); } }
        } else {
            WAITVM(0);
        }
        barrier_fence();                    // all waves' k-tiles landed

        const char* Ac = lds + cur * ABSZ;
        const char* Bc = lds + BOFF + cur * BSZ;
        bf16x8 a[MI][2];
#pragma unroll
        for (int mi = 0; mi < MI; ++mi) {
            int ar = wid * 32 + mi * 16 + col;
#pragma unroll
            for (int kk = 0; kk < 2; ++kk)
                a[mi][kk] = *(const bf16x8*)(Ac + ((ar * 128 + kk * 64 + kgrp * 16)
                                                   ^ ((ar & 7) << 4)));
        }
#pragma unroll
        for (int kk = 0; kk < 2; ++kk)
#pragma unroll
            for (int ni = 0; ni < NI; ++ni) {
                int br = ni * 16 + col;
                bf16x8 b = *(const bf16x8*)(Bc + ((br * 128 + kk * 64 + kgrp * 16)
                                                  ^ ((br & 7) << 4)));
#pragma unroll
                for (int mi = 0; mi < MI; ++mi)
                    acc[mi][ni] = __builtin_amdgcn_mfma_f32_16x16x32_bf16(
                        a[mi][kk], b, acc[mi][ni], 0, 0, 0);
            }
    }

    // ---- epilogue: C/D layout col=lane&15, row=(lane>>4)*4+reg ----
#pragma unroll
    for (int ni = 0; ni < NI; ++ni) {
        float bv = bias[ni * 16 + col];
#pragma unroll
        for (int mi = 0; mi < MI; ++mi) {
#pragma unroll
            for (int reg = 0; reg < 4; ++reg) {
                int r = row0 + wid * 32 + mi * 16 + kgrp * 4 + reg;
                float v = acc[mi][ni][reg] + bv;
                if (RELU) v = fmaxf(v, 0.f);
                if (OUT_F32) ((float*)dst)[(size_t)r * NCOLS + ni * 16 + col] = v;
                else ((__bf16*)dst)[(size_t)r * NCOLS + ni * 16 + col] = (__bf16)v;
            }
        }
    }
}

extern "C" void kernel_launch(void* const* d_in, const int* in_sizes, int n_in,
                              void* d_out, int out_size, void* d_ws, size_t ws_size,
                              hipStream_t stream) {
    const float* x  = (const float*)d_in[0];
    const int* nidx = (const int*)d_in[1];
    const float* W1 = (const float*)d_in[2];
    const float* b1 = (const float*)d_in[3];
    const float* W2 = (const float*)d_in[4];
    const float* b2 = (const float*)d_in[5];
    const float* W3 = (const float*)d_in[6];
    const float* b3 = (const float*)d_in[7];

    // ws: buf0(8MB: xb, later h2) | buf1(8MB: h1) | Wt1 | Wt2 | Wt3 | zeropage
    char* ws = (char*)d_ws;
    __bf16* buf0 = (__bf16*)ws;
    __bf16* buf1 = (__bf16*)(ws + 8388608);
    __bf16* Wt1  = (__bf16*)(ws + 16777216);
    __bf16* Wt2  = Wt1 + 27 * 64 * 64;
    __bf16* Wt3  = Wt2 + 27 * 64 * 64;
    __bf16* zp   = Wt3 + 27 * 16 * 64;   // 256B-aligned

    prep_kernel<<<PREP_GRID, 256, 0, stream>>>(x, W1, W2, W3, buf0, Wt1, Wt2, Wt3, (float*)zp);

    dim3 grid(N_VOX / BR);
    conv_layer<64, true,  false><<<grid, 256, 0, stream>>>(buf0, nidx, Wt1, b1, buf1, zp);
    conv_layer<64, true,  false><<<grid, 256, 0, stream>>>(buf1, nidx, Wt2, b2, buf0, zp);
    conv_layer<16, false, true ><<<grid, 256, 0, stream>>>(buf0, nidx, Wt3, b3, d_out, zp);
}